// Round 1
// baseline (232.273 us; speedup 1.0000x reference)
//
#include <hip/hip_runtime.h>

#define B_ 16
#define L_ 512
#define H_ 256
#define V_ 32000
#define HALF_ 128

typedef __attribute__((ext_vector_type(8))) short short8;
typedef __attribute__((ext_vector_type(4))) float floatx4;

__device__ __forceinline__ unsigned short f2bf(float x) {
  unsigned int u = __float_as_uint(x);
  unsigned int r = (u + 0x7FFFu + ((u >> 16) & 1u)) >> 16;
  return (unsigned short)r;
}

template <int CTRL>
__device__ __forceinline__ float dpp_xor_add(float x) {
  int y = __builtin_amdgcn_mov_dpp(__float_as_int(x), CTRL, 0xf, 0xf, true);
  return x + __int_as_float(y);
}

// butterfly sum over aligned 16-lane groups; ALL lanes get the result
__device__ __forceinline__ float redu16(float p) {
  p = dpp_xor_add<0xB1>(p);   // xor1
  p = dpp_xor_add<0x4E>(p);   // xor2
  p = dpp_xor_add<0x141>(p);  // row_half_mirror
  p = dpp_xor_add<0x140>(p);  // row_mirror
  return p;
}

// async global->LDS copy, 16B per lane, wave-uniform LDS base
__device__ __forceinline__ void async_cp16(const float* g, float* l) {
  __builtin_amdgcn_global_load_lds(
      (const __attribute__((address_space(1))) void*)g,
      (__attribute__((address_space(3))) void*)l, 16, 0, 0);
}

__device__ __forceinline__ float dot8(const float* a, const float* b) {
  float t0 = a[0] * b[0] + a[1] * b[1];
  float t1 = a[2] * b[2] + a[3] * b[3];
  float t2 = a[4] * b[4] + a[5] * b[5];
  float t3 = a[6] * b[6] + a[7] * b[7];
  return (t0 + t1) + (t2 + t3);
}

// ---------------- prep: embedding gather (fp32+bf16) + weight bf16 conversion ----------------
__global__ __launch_bounds__(256) void prep_kernel(const int* __restrict__ seq,
                                                   const float* __restrict__ embed,
                                                   float* __restrict__ h,
                                                   unsigned short* __restrict__ hbf,
                                                   const float* __restrict__ W1,
                                                   const float* __restrict__ W2,
                                                   const float* __restrict__ Ws,
                                                   const float* __restrict__ We,
                                                   unsigned short* __restrict__ W1b,
                                                   unsigned short* __restrict__ W2b,
                                                   unsigned short* __restrict__ Wcb) {
  int blk = blockIdx.x;
  int tid = threadIdx.x;
  if (blk < 2048) {
    int token = blk * 4 + (tid >> 6);
    int lane = tid & 63;
    int row = seq[token];
    float4 v = ((const float4*)(embed + (size_t)row * H_))[lane];
    ((float4*)(h + (size_t)token * H_))[lane] = v;
    ushort4 o;
    o.x = f2bf(v.x); o.y = f2bf(v.y); o.z = f2bf(v.z); o.w = f2bf(v.w);
    *(ushort4*)(hbf + (size_t)token * H_ + lane * 4) = o;
  } else {
    int i = (blk - 2048) * 256 + tid;  // 0..327679
    if (i < 131072) W1b[i] = f2bf(W1[i]);
    else if (i < 262144) W2b[i - 131072] = f2bf(W2[i - 131072]);
    else if (i < 294912) Wcb[i - 262144] = f2bf(Ws[i - 262144]);
    else Wcb[i - 262144] = f2bf(We[i - 294912]);
  }
}

// ---------------- bf16 MFMA GEMM with global prefetch: C = act(A @ B^T + bias + Res) ----------------
template <int MT, bool RELU, bool BIAS, bool RES, bool OUT_BF16>
__global__ __launch_bounds__(256) void gemm_mfma(const unsigned short* __restrict__ A,
                                                 const unsigned short* __restrict__ Bw,
                                                 const float* __restrict__ bias,
                                                 const float* __restrict__ Res,
                                                 float* __restrict__ Cf,
                                                 unsigned short* __restrict__ Cb,
                                                 int M, int N, int K) {
  constexpr int FI = MT / 32;
  __shared__ unsigned short As[MT * 40];
  __shared__ unsigned short Bs[128 * 40];
  int tid = threadIdx.x;
  int wave = tid >> 6, lane = tid & 63;
  int wm = (wave >> 1) * (MT / 2), wn = (wave & 1) * 64;
  int quad = lane >> 4, l15 = lane & 15;
  int bm = blockIdx.y * MT, bn = blockIdx.x * 128;
  int sr = tid >> 2, sq = tid & 3;

  floatx4 zero = {0.f, 0.f, 0.f, 0.f};
  floatx4 acc[FI][4];
#pragma unroll
  for (int fi = 0; fi < FI; fi++)
#pragma unroll
    for (int fj = 0; fj < 4; fj++) acc[fi][fj] = zero;

  // prefetch chunk 0
  uint4 av0, av1, bv0, bv1;
  av0 = *(const uint4*)(A + (size_t)(bm + sr) * K + sq * 8);
  if (MT == 128) av1 = *(const uint4*)(A + (size_t)(bm + 64 + sr) * K + sq * 8);
  bv0 = *(const uint4*)(Bw + (size_t)(bn + sr) * K + sq * 8);
  bv1 = *(const uint4*)(Bw + (size_t)(bn + 64 + sr) * K + sq * 8);

  for (int k0 = 0; k0 < K; k0 += 32) {
    __syncthreads();
    *(uint4*)(As + sr * 40 + sq * 8) = av0;
    if (MT == 128) *(uint4*)(As + (64 + sr) * 40 + sq * 8) = av1;
    *(uint4*)(Bs + sr * 40 + sq * 8) = bv0;
    *(uint4*)(Bs + (64 + sr) * 40 + sq * 8) = bv1;
    __syncthreads();
    if (k0 + 32 < K) {  // prefetch next chunk while MFMAs run
      av0 = *(const uint4*)(A + (size_t)(bm + sr) * K + k0 + 32 + sq * 8);
      if (MT == 128) av1 = *(const uint4*)(A + (size_t)(bm + 64 + sr) * K + k0 + 32 + sq * 8);
      bv0 = *(const uint4*)(Bw + (size_t)(bn + sr) * K + k0 + 32 + sq * 8);
      bv1 = *(const uint4*)(Bw + (size_t)(bn + 64 + sr) * K + k0 + 32 + sq * 8);
    }
    short8 af[FI], bf[4];
#pragma unroll
    for (int f = 0; f < FI; f++) af[f] = *(const short8*)(As + (wm + f * 16 + l15) * 40 + quad * 8);
#pragma unroll
    for (int f = 0; f < 4; f++) bf[f] = *(const short8*)(Bs + (wn + f * 16 + l15) * 40 + quad * 8);
#pragma unroll
    for (int fi = 0; fi < FI; fi++)
#pragma unroll
      for (int fj = 0; fj < 4; fj++)
        acc[fi][fj] = __builtin_amdgcn_mfma_f32_16x16x32_bf16(af[fi], bf[fj], acc[fi][fj], 0, 0, 0);
  }

#pragma unroll
  for (int fi = 0; fi < FI; fi++) {
#pragma unroll
    for (int fj = 0; fj < 4; fj++) {
      int col = bn + wn + fj * 16 + l15;
      float bb = BIAS ? bias[col] : 0.f;
#pragma unroll
      for (int rg = 0; rg < 4; rg++) {
        int row = bm + wm + fi * 16 + quad * 4 + rg;
        float v = acc[fi][fj][rg] + bb;
        if (RES) v += Res[(size_t)row * N + col];
        if (RELU) v = fmaxf(v, 0.f);
        if (OUT_BF16) Cb[(size_t)row * N + col] = f2bf(v);
        else Cf[(size_t)row * N + col] = v;
      }
    }
  }
}

// ---------------- LayerNorm over H=256, one wave per row; bf16 output ----------------
__global__ void ln_kernel(const float* __restrict__ x, const float* __restrict__ gamma,
                          const float* __restrict__ beta, unsigned short* __restrict__ yb) {
  int row = blockIdx.x;
  int lane = threadIdx.x;  // 64
  float4 v = ((const float4*)(x + (size_t)row * H_))[lane];
  float s = v.x + v.y + v.z + v.w;
  float sq = v.x * v.x + v.y * v.y + v.z * v.z + v.w * v.w;
#pragma unroll
  for (int off = 32; off >= 1; off >>= 1) {
    s += __shfl_xor(s, off);
    sq += __shfl_xor(sq, off);
  }
  float mu = s * (1.f / H_);
  float var = sq * (1.f / H_) - mu * mu;
  float inv = rsqrtf(var + 1e-5f);
  float4 g = ((const float4*)gamma)[lane];
  float4 b = ((const float4*)beta)[lane];
  ushort4 o;
  o.x = f2bf((v.x - mu) * inv * g.x + b.x);
  o.y = f2bf((v.y - mu) * inv * g.y + b.y);
  o.z = f2bf((v.z - mu) * inv * g.z + b.z);
  o.w = f2bf((v.w - mu) * inv * g.w + b.w);
  *(ushort4*)(yb + (size_t)row * H_ + lane * 4) = o;
}

// ---------------- KPROJ: k = hn @ [Wsem;Wepi]^T; khat fp32 (granule-permuted) + raw kT ----------------
__global__ __launch_bounds__(256) void kproj_kernel(const unsigned short* __restrict__ hnb,
                                                    const unsigned short* __restrict__ Wcb,
                                                    float* __restrict__ khat,
                                                    float* __restrict__ kT) {
  __shared__ unsigned short As[32 * 40];
  __shared__ unsigned short Bs[256 * 40];
  int tid = threadIdx.x;
  int wave = tid >> 6, lane = tid & 63;
  int wm = (wave >> 1) * 16, wnh = wave & 1, wn = wnh * 128;
  int quad = lane >> 4, l15 = lane & 15;
  int bm = blockIdx.x * 32;

  floatx4 zero = {0.f, 0.f, 0.f, 0.f};
  floatx4 acc[8];
#pragma unroll
  for (int fj = 0; fj < 8; fj++) acc[fj] = zero;

  int sr = tid >> 2, sq = tid & 3;
  uint4 av, bv[4];
  if (tid < 128) av = *(const uint4*)(hnb + (size_t)(bm + sr) * H_ + sq * 8);
#pragma unroll
  for (int q = 0; q < 4; q++) {
    int unit = q * 256 + tid;
    bv[q] = *(const uint4*)(Wcb + (size_t)(unit >> 2) * H_ + (unit & 3) * 8);
  }

  for (int k0 = 0; k0 < 256; k0 += 32) {
    __syncthreads();
    if (tid < 128) *(uint4*)(As + sr * 40 + sq * 8) = av;
#pragma unroll
    for (int q = 0; q < 4; q++) {
      int unit = q * 256 + tid;
      *(uint4*)(Bs + (unit >> 2) * 40 + (unit & 3) * 8) = bv[q];
    }
    __syncthreads();
    if (k0 + 32 < 256) {
      if (tid < 128) av = *(const uint4*)(hnb + (size_t)(bm + sr) * H_ + k0 + 32 + sq * 8);
#pragma unroll
      for (int q = 0; q < 4; q++) {
        int unit = q * 256 + tid;
        bv[q] = *(const uint4*)(Wcb + (size_t)(unit >> 2) * H_ + k0 + 32 + (unit & 3) * 8);
      }
    }
    short8 af = *(const short8*)(As + (wm + l15) * 40 + quad * 8);
    short8 bf[8];
#pragma unroll
    for (int fj = 0; fj < 8; fj++)
      bf[fj] = *(const short8*)(Bs + (wn + fj * 16 + l15) * 40 + quad * 8);
#pragma unroll
    for (int fj = 0; fj < 8; fj++)
      acc[fj] = __builtin_amdgcn_mfma_f32_16x16x32_bf16(af, bf[fj], acc[fj], 0, 0, 0);
  }

  // epilogue: per-row L2 norm over this wave's 128-col half
  int b = bm >> 9;
  int idxm = b * 2 + wnh;
  int tloc0 = (bm & 511) + wm + quad * 4;
  float inv[4];
#pragma unroll
  for (int rg = 0; rg < 4; rg++) {
    float ssq = 0.f;
#pragma unroll
    for (int fj = 0; fj < 8; fj++) ssq += acc[fj][rg] * acc[fj][rg];
    ssq = redu16(ssq);
    inv[rg] = 1.f / fmaxf(sqrtf(ssq), 1e-12f);
  }
#pragma unroll
  for (int fj = 0; fj < 8; fj++) {
    int ch = fj * 16 + l15;             // logical col 0..127
    int j = ch >> 2, e = ch & 3;        // float4 granule + elem
    int pj = (j & 1) ? (16 + (j >> 1)) : (j >> 1);  // even granules first
    int pcol = pj * 4 + e;
#pragma unroll
    for (int rg = 0; rg < 4; rg++)
      khat[((size_t)idxm * L_ + tloc0 + rg) * HALF_ + pcol] = acc[fj][rg] * inv[rg];
    float4 raw = {acc[fj][0], acc[fj][1], acc[fj][2], acc[fj][3]};
    *(float4*)(kT + (size_t)idxm * (HALF_ * L_) + (size_t)ch * L_ + tloc0) = raw;
  }
}

// ---------------- scan: 4-step WY look-ahead + LDS-staged khat and raw keys ----------------
// Group of 4 steps from group-start state M0:
//   P_u = M0 . khat_u                      (4 independent redu16'd dots)
//   s_u = k_u - P_u - sum_{v<u} s_v a_uv   (a_uv = khat_v . khat_u, precomputed per chunk)
//   M  += sum_u s_u khat_u^T               (rank-4 batched update)
// Exact same math as the serial delta rule up to fp32 reassociation.

#define LOADPK(P, TL)                                                          \
  do {                                                                         \
    _Pragma("unroll") for (int u_ = 0; u_ < 4; u_++) {                         \
      *(float4*)&P[u_][0] = *(const float4*)(base + ((TL) + u_) * 128);        \
      *(float4*)&P[u_][4] = *(const float4*)(base + ((TL) + u_) * 128 + 64);   \
    }                                                                          \
  } while (0)

#define GRP4(P, PN, TL, DOLOAD)                                                \
  do {                                                                         \
    if (DOLOAD) LOADPK(PN, (TL) + 4);                                          \
    float4 krc_ = *(const float4*)(krp + (TL));                                \
    float4 aA_ = *(const float4*)&a_s[(TL) >> 2][0];                           \
    float2 aB_ = *(const float2*)&a_s[(TL) >> 2][4];                           \
    float P0_ = redu16(dot8(m, P[0]));                                         \
    float P1_ = redu16(dot8(m, P[1]));                                         \
    float P2_ = redu16(dot8(m, P[2]));                                         \
    float P3_ = redu16(dot8(m, P[3]));                                         \
    float s0_ = krc_.x - P0_;                                                  \
    float s1_ = (krc_.y - P1_) - s0_ * aA_.x;                                  \
    float s2_ = (krc_.z - P2_) - (s0_ * aA_.y + s1_ * aA_.z);                  \
    float s3_ = (krc_.w - P3_) - ((s0_ * aA_.w + s1_ * aB_.x) + s2_ * aB_.y);  \
    _Pragma("unroll") for (int j_ = 0; j_ < 8; j_++) {                         \
      float mm_ = m[j_];                                                       \
      mm_ += s0_ * P[0][j_];                                                   \
      mm_ += s1_ * P[1][j_];                                                   \
      mm_ += s2_ * P[2][j_];                                                   \
      mm_ += s3_ * P[3][j_];                                                   \
      m[j_] = mm_;                                                             \
    }                                                                          \
  } while (0)

__global__ __launch_bounds__(256) void scan_kernel(const float* __restrict__ khat,
                                                   const float* __restrict__ kT,
                                                   float* __restrict__ c) {
  __shared__ float sk[2][64 * 128];   // khat double buffer (64 KB)
  __shared__ float krs[16 * 520];     // raw keys, padded rows (33 KB)
  __shared__ float a_s[16][8];        // per-group gram dots (6 used)
  int bid = blockIdx.x;
  int idxm = bid & 31;
  int rg = bid >> 5;
  int b = idxm >> 1, mat = idxm & 1;
  const float* kh = khat + (size_t)idxm * L_ * HALF_;
  const float* kTi = kT + (size_t)idxm * HALF_ * L_;

  int tid = threadIdx.x;
  int wv = tid >> 6, ln = tid & 63;
  int seg = tid & 15, rl = tid >> 4;
  int r = rg * 16 + rl;
  int c0 = seg * 8;

  float m[8];
#pragma unroll
  for (int g = 0; g < 8; g++) m[g] = 0.f;

  // prologue: load this block's 16 raw-key rows (32 KB, padded into LDS)
  // + async-stage khat chunk 0; one barrier drains both.
  {
    const float* gk = kTi + (size_t)rg * 16 * 512;
    float4 krv[8];
#pragma unroll
    for (int j = 0; j < 8; j++) krv[j] = *(const float4*)(gk + wv * 2048 + j * 256 + ln * 4);
    const float* g0 = kh + wv * 2048 + ln * 4;
    float* l0 = &sk[0][wv * 2048];
#pragma unroll
    for (int j = 0; j < 8; j++) async_cp16(g0 + j * 256, l0 + j * 256);
#pragma unroll
    for (int j = 0; j < 8; j++) {
      int idx = wv * 2048 + j * 256 + ln * 4;
      *(float4*)(krs + (idx >> 9) * 520 + (idx & 511)) = krv[j];
    }
  }
  __syncthreads();

  for (int ch = 0; ch < 8; ch++) {
    if (ch < 7) {  // stage next chunk (drains at end-of-chunk barrier)
      const float* gs = kh + (size_t)(ch + 1) * 8192 + wv * 2048 + ln * 4;
      float* ls = &sk[(ch + 1) & 1][wv * 2048];
#pragma unroll
      for (int j = 0; j < 8; j++) async_cp16(gs + j * 256, ls + j * 256);
    }
    const float* base = &sk[ch & 1][0] + seg * 4;
    {  // gram dots: rl-group computes the 6 in-group dots of local group rl
      float kv[4][8];
#pragma unroll
      for (int u = 0; u < 4; u++) {
        *(float4*)&kv[u][0] = *(const float4*)(base + (rl * 4 + u) * 128);
        *(float4*)&kv[u][4] = *(const float4*)(base + (rl * 4 + u) * 128 + 64);
      }
      float d10 = redu16(dot8(kv[1], kv[0]));
      float d20 = redu16(dot8(kv[2], kv[0]));
      float d21 = redu16(dot8(kv[2], kv[1]));
      float d30 = redu16(dot8(kv[3], kv[0]));
      float d31 = redu16(dot8(kv[3], kv[1]));
      float d32 = redu16(dot8(kv[3], kv[2]));
      if (seg == 0) {
        a_s[rl][0] = d10; a_s[rl][1] = d20; a_s[rl][2] = d21;
        a_s[rl][3] = d30; a_s[rl][4] = d31; a_s[rl][5] = d32;
      }
    }
    __syncthreads();  // publish a_s

    const float* krp = krs + rl * 520 + ch * 64;
    float pA[4][8], pB[4][8];
    LOADPK(pA, 0);
    for (int g = 0; g < 7; g++) {  // groups 0..13, software-pipelined pk loads
      GRP4(pA, pB, g * 8, 1);
      GRP4(pB, pA, g * 8 + 4, 1);
    }
    GRP4(pA, pB, 56, 1);  // group 14, loads rows 60..63 into pB
    if (ch < 7) {
      GRP4(pB, pA, 60, 0);  // group 15
    } else {  // chunk 7 tail: steps 508..510 (3 updates)
      float4 krc = *(const float4*)(krp + 60);
      float4 aA = *(const float4*)&a_s[15][0];
      float P0 = redu16(dot8(m, pB[0]));
      float P1 = redu16(dot8(m, pB[1]));
      float P2 = redu16(dot8(m, pB[2]));
      float s0 = krc.x - P0;
      float s1 = (krc.y - P1) - s0 * aA.x;
      float s2 = (krc.z - P2) - (s0 * aA.y + s1 * aA.z);
#pragma unroll
      for (int j = 0; j < 8; j++)
        m[j] += s0 * pB[0][j] + s1 * pB[1][j] + s2 * pB[2][j];
    }
    __syncthreads();  // reads of buf[ch&1]/a_s done; staged buf[(ch+1)&1] drained
  }

  // final read with raw last-token key (t=511), gathered from kT columns
  float q[8];
#pragma unroll
  for (int j = 0; j < 8; j++) q[j] = kTi[(size_t)(c0 + j) * L_ + 511];
  float p = redu16(dot8(m, q));
  if (seg == 0) c[(size_t)b * H_ + mat * HALF_ + r] = p;
}

// ---------------- r = c @ W_rp^T + b_rp ----------------
__global__ void rp_kernel(const float* __restrict__ c, const float* __restrict__ Wrp,
                          const float* __restrict__ brp, float* __restrict__ r) {
  int b = blockIdx.x;
  int n = threadIdx.x;  // 256
  __shared__ float cs[H_];
  cs[n] = c[(size_t)b * H_ + n];
  __syncthreads();
  const float4* w4 = (const float4*)(Wrp + (size_t)n * H_);
  const float4* c4 = (const float4*)cs;
  float acc = 0.f;
#pragma unroll 8
  for (int k = 0; k < H_ / 4; k++) {
    float4 w = w4[k], cc = c4[k];
    acc += w.x * cc.x + w.y * cc.y + w.z * cc.z + w.w * cc.w;
  }
  r[(size_t)b * H_ + n] = acc + brp[n];
}

// ---------------- out = r @ W_out^T + b_out, coalesced ----------------
__global__ __launch_bounds__(256) void out_kernel(const float* __restrict__ r,
                                                  const float* __restrict__ Wout,
                                                  const float* __restrict__ bout,
                                                  float* __restrict__ out) {
  __shared__ float rs[16 * 272];
  __shared__ float obuf[16 * 68];
  int tid = threadIdx.x;
#pragma unroll
  for (int q = 0; q < 16; q++) {
    int idx = q * 256 + tid;
    int bb = idx >> 8, cc = idx & 255;
    rs[bb * 272 + cc + 4 * (cc >> 6)] = r[idx];
  }
  __syncthreads();
  int row = tid >> 2, part = tid & 3;
  int v = blockIdx.x * 64 + row;
  const float4* w4 = (const float4*)(Wout + (size_t)v * H_ + part * 64);
  float acc[16];
#pragma unroll
  for (int bb = 0; bb < 16; bb++) acc[bb] = 0.f;
#pragma unroll 4
  for (int j = 0; j < 16; j++) {
    float4 w = w4[j];
#pragma unroll
    for (int bb = 0; bb < 16; bb++) {
      float4 rv = *(const float4*)&rs[bb * 272 + part * 68 + j * 4];
      acc[bb] += w.x * rv.x + w.y * rv.y + w.z * rv.z + w.w * rv.w;
    }
  }
  float bo = bout[v];
#pragma unroll
  for (int bb = 0; bb < 16; bb++) {
    acc[bb] = dpp_xor_add<0xB1>(acc[bb]);
    acc[bb] = dpp_xor_add<0x4E>(acc[bb]);
  }
#pragma unroll
  for (int q = 0; q < 4; q++) {
    int bb = part * 4 + q;
    obuf[bb * 68 + row] = acc[bb] + bo;
  }
  __syncthreads();
#pragma unroll
  for (int q = 0; q < 4; q++) {
    int idx = q * 256 + tid;
    int bb = idx >> 6, vl = idx & 63;
    out[(size_t)bb * V_ + blockIdx.x * 64 + vl] = obuf[bb * 68 + vl];
  }
}

extern "C" void kernel_launch(void* const* d_in, const int* in_sizes, int n_in,
                              void* d_out, int out_size, void* d_ws, size_t ws_size,
                              hipStream_t stream) {
  const int* seq = (const int*)d_in[0];
  const float* embed = (const float*)d_in[1];
  const float* W1 = (const float*)d_in[2];
  const float* b1 = (const float*)d_in[3];
  const float* W2 = (const float*)d_in[4];
  const float* b2 = (const float*)d_in[5];
  const float* gamma = (const float*)d_in[6];
  const float* beta = (const float*)d_in[7];
  const float* Wsem = (const float*)d_in[8];
  const float* Wepi = (const float*)d_in[9];
  const float* Wrp = (const float*)d_in[10];
  const float* brp = (const float*)d_in[11];
  const float* Wout = (const float*)d_in[12];
  const float* bout = (const float*)d_in[13];
  float* out = (float*)d_out;

  // Workspace layout (float-slot offsets), NO overlapping live ranges:
  //  [0        , 2097152 )  h fp32 (x in-place)  -> later kT (h dead after ln)
  //  [2097152  , 4194304 )  a1b bf16 [8192,512]  -> later khat (a1b dead after gemm2)
  //  [4194304  , 5242880 )  hbf bf16 [8192,256]
  //  [5242880  , 6291456 )  hnb bf16 [8192,256]
  //  [6291456  , 6356992 )  W1b bf16 131072
  //  [6356992  , 6422528 )  W2b bf16 131072
  //  [6422528  , 6455296 )  Wcb bf16 65536
  //  [6455296  , 6459392 )  c  [16,256]
  //  [6459392  , 6463488 )  r  [16,256]
  float* ws = (float*)d_ws;
  float* h = ws;
  float* kT = ws;
  unsigned short* a1b = (unsigned short*)(ws + 2097152);
  float* khat = ws + 2097152;
  unsigned short* hbf = (unsigned short*)(ws + 4194304);
  unsigned short* hnb = (unsigned short*)(ws + 5242880);
  unsigned short* W1b = (unsigned short*)(ws + 6291456);
  unsigned short* W2b = (unsigned short*)(ws + 6356992);
  unsigned short* Wcb = (unsigned short*)(ws + 6422528);
  float* c = ws + 6455296;
  float* r = ws + 6459392;

  // 1. gather (h fp32 + hbf bf16) + weight conversion
  prep_kernel<<<3328, 256, 0, stream>>>(seq, embed, h, hbf, W1, W2, Wsem, Wepi, W1b, W2b, Wcb);
  // 2. a1 = relu(h @ W1^T + b1) -> bf16
  gemm_mfma<128, true, true, false, true><<<dim3(4, 64), 256, 0, stream>>>(
      hbf, W1b, b1, nullptr, nullptr, a1b, 8192, 512, 256);
  // 3. x = a1 @ W2^T + b2 + h -> fp32 in-place over h
  gemm_mfma<64, false, true, true, false><<<dim3(2, 128), 256, 0, stream>>>(
      a1b, W2b, b2, h, h, nullptr, 8192, 256, 512);
  // 4. hn = LayerNorm(x) -> bf16
  ln_kernel<<<8192, 64, 0, stream>>>(h, gamma, beta, hnb);
  // 5. k-projection + normalize + permute/transpose (khat over a1b, kT over h)
  kproj_kernel<<<256, 256, 0, stream>>>(hnb, Wcb, khat, kT);
  // 6. delta-rule scan -> c [16,256]
  scan_kernel<<<256, 256, 0, stream>>>(khat, kT, c);
  // 7. r = c @ Wrp^T + brp
  rp_kernel<<<16, 256, 0, stream>>>(c, Wrp, brp, r);
  // 8. out = r @ Wout^T + bout
  out_kernel<<<500, 256, 0, stream>>>(r, Wout, bout, out);
}